// Round 1
// baseline (3151.437 us; speedup 1.0000x reference)
//
#include <hip/hip_runtime.h>

// B=2048, T=128, D=5, H=256. Two sequential LSTM scans; batch-sliced
// persistent workgroups (16 rows/WG, grid=128, 8 waves of 64).
// gates[16 x 1024] = MFMA_bf16( [h | x | 0]  x  [W_hh | W_ih | 0]^T ), K=288.
// Weights pre-packed into MFMA fragment order by prep kernels.

typedef __bf16 bf16x8 __attribute__((ext_vector_type(8)));
typedef float f32x4 __attribute__((ext_vector_type(4)));

#define MFMA16(a, b, c) __builtin_amdgcn_mfma_f32_16x16x32_bf16((a), (b), (c), 0, 0, 0)
#define LROW 296  // LDS row stride (elements): 296*2B=592B -> 2-way bank alias (free)

__device__ __forceinline__ float fast_sigmoid(float x) {
  float e = __builtin_amdgcn_exp2f(-1.4426950408889634f * x);
  return __builtin_amdgcn_rcpf(1.0f + e);
}
__device__ __forceinline__ float fast_tanh(float x) {
  float e = __builtin_amdgcn_exp2f(2.8853900817779268f * x);
  return 1.0f - 2.0f * __builtin_amdgcn_rcpf(e + 1.0f);
}
__device__ __forceinline__ float lrelu(float x) { return x >= 0.0f ? x : 0.01f * x; }

// ---------------- prep: pack weights into per-(gate-tile,chunk,lane) fragments ----------------
// wpack fragment (gt,c,lane): 8 bf16 = W[g=gt*16+(lane&15)][k = c*32+(lane>>4)*8 + 0..7]
__global__ void pack_gates_k(const float* __restrict__ Whh, const float* __restrict__ Wih,
                             const float* __restrict__ bih, const float* __restrict__ bhh,
                             __bf16* __restrict__ wpack, __bf16* __restrict__ ihpack,
                             float* __restrict__ bias) {
  int lane = threadIdx.x;
  int blk = blockIdx.x;
  if (blk < 512) {  // W_hh chunks 0..7 (k<256)
    int gt = blk >> 3, c = blk & 7;
    int g = gt * 16 + (lane & 15);
    int k0 = c * 32 + (lane >> 4) * 8;
    bf16x8 v;
#pragma unroll
    for (int j = 0; j < 8; ++j) v[j] = (__bf16)Whh[g * 256 + k0 + j];
    *(bf16x8*)(wpack + ((size_t)(gt * 8 + c) * 64 + lane) * 8) = v;
  } else if (blk < 576) {  // W_ih chunk (k=256..287 -> x[0..4], zero pad)
    int gt = blk - 512;
    int g = gt * 16 + (lane & 15);
    int kk = (lane >> 4) * 8;
    bf16x8 v;
#pragma unroll
    for (int j = 0; j < 8; ++j) {
      float f = (kk + j < 5) ? Wih[g * 5 + kk + j] : 0.0f;
      v[j] = (__bf16)f;
    }
    *(bf16x8*)(ihpack + ((size_t)gt * 64 + lane) * 8) = v;
  } else {  // combined bias
    int g = (blk - 576) * 64 + lane;
    bias[g] = bih[g] + bhh[g];
  }
}

__global__ void pack_enc_k(const float* __restrict__ Wenc, __bf16* __restrict__ encpack) {
  int lane = threadIdx.x;
  int gt = blockIdx.x >> 3, c = blockIdx.x & 7;
  int j_row = gt * 16 + (lane & 15);
  int k0 = c * 32 + (lane >> 4) * 8;
  bf16x8 v;
#pragma unroll
  for (int j = 0; j < 8; ++j) v[j] = (__bf16)Wenc[j_row * 512 + k0 + j];  // cols 0..255 of (256,512)
  *(bf16x8*)(encpack + ((size_t)(gt * 8 + c) * 64 + lane) * 8) = v;
}

__global__ void pack_out_k(const float* __restrict__ Wout, __bf16* __restrict__ outpack) {
  int lane = threadIdx.x;
  int c = blockIdx.x;
  int d = lane & 15;
  int k0 = c * 32 + (lane >> 4) * 8;
  bf16x8 v;
#pragma unroll
  for (int j = 0; j < 8; ++j) v[j] = (d < 5) ? (__bf16)Wout[d * 256 + k0 + j] : (__bf16)0.0f;
  *(bf16x8*)(outpack + ((size_t)c * 64 + lane) * 8) = v;
}

// ---------------- main fused kernel ----------------
__global__ __launch_bounds__(512) void rnn_fused(
    const float* __restrict__ sk, const float* __restrict__ initx,
    const bf16x8* __restrict__ Wg, const bf16x8* __restrict__ Wgih, const float* __restrict__ biasg,
    const bf16x8* __restrict__ Wf, const bf16x8* __restrict__ Wfih, const float* __restrict__ biasf,
    const bf16x8* __restrict__ Wenc, const float* __restrict__ benc,
    const bf16x8* __restrict__ Wout, const float* __restrict__ bout,
    float* __restrict__ out) {
  // hbuf[b][r][k]: k<256 = h (bf16), k=256..260 = x, k=261.. = 0. Ping-pong buffers.
  __shared__ __bf16 hbuf[2][16][LROW];
  const int tid = threadIdx.x;
  const int lane = tid & 63;
  const int wv = tid >> 6;    // wave 0..7; owns hidden units j in [wv*32, wv*32+32)
  const int col = lane & 15;  // MFMA: A-row / B-col / C-col
  const int lgrp = lane >> 4; // MFMA: k-group / C-row-group
  const int b0 = blockIdx.x * 16;
  const int ut2 = wv * 2;     // base unit-tile (16 units each)

  // zero LDS (covers h region, x slot, zero-pad k>=261)
  for (int i = tid; i < 2 * 16 * LROW; i += 512) (&hbuf[0][0][0])[i] = (__bf16)0.0f;
  __syncthreads();

  // stage x(0) for encoder
  if (tid < 80) {
    int r = tid / 5, d = tid - (tid / 5) * 5;
    hbuf[0][r][256 + d] = (__bf16)sk[((size_t)(b0 + r) * 128 + 0) * 5 + d];
  }

  float c_reg[2][4];
#pragma unroll
  for (int p = 0; p < 2; ++p)
#pragma unroll
    for (int r = 0; r < 4; ++r) c_reg[p][r] = 0.0f;

  // encoder-phase constants
  float bias_v[8];
  bf16x8 wih[8];
#pragma unroll
  for (int p = 0; p < 2; ++p)
#pragma unroll
    for (int q = 0; q < 4; ++q) {
      bias_v[p * 4 + q] = biasf[q * 256 + (ut2 + p) * 16 + col];
      wih[p * 4 + q] = Wfih[(q * 16 + ut2 + p) * 64 + lane];
    }

  __syncthreads();

  bf16x8 a[9];
#pragma unroll
  for (int c = 0; c < 9; ++c) a[c] = *(const bf16x8*)&hbuf[0][col][c * 32 + lgrp * 8];

  // one LSTM step: gates MFMA (K=288) + elementwise; writes h_new (bf16) to wb
  auto lstm_step = [&](const bf16x8* __restrict__ Wp, __bf16(*wb)[LROW]) {
#pragma unroll
    for (int p = 0; p < 2; ++p) {
      f32x4 accs[4];
#pragma unroll
      for (int q = 0; q < 4; ++q) {
        const int gt = q * 16 + ut2 + p;
        bf16x8 bb[8];
#pragma unroll
        for (int c = 0; c < 8; ++c) bb[c] = Wp[(gt * 8 + c) * 64 + lane];
        const float bv = bias_v[p * 4 + q];
        f32x4 acc = {bv, bv, bv, bv};
#pragma unroll
        for (int c = 0; c < 8; ++c) acc = MFMA16(a[c], bb[c], acc);
        acc = MFMA16(a[8], wih[p * 4 + q], acc);  // x-chunk (weights register-resident)
        accs[q] = acc;
      }
#pragma unroll
      for (int r = 0; r < 4; ++r) {
        float ig = fast_sigmoid(accs[0][r]);
        float fg = fast_sigmoid(accs[1][r]);
        float gg = fast_tanh(accs[2][r]);
        float og = fast_sigmoid(accs[3][r]);
        float cn = fg * c_reg[p][r] + ig * gg;
        c_reg[p][r] = cn;
        float hn = og * fast_tanh(cn);
        wb[lgrp * 4 + r][(ut2 + p) * 16 + col] = (__bf16)hn;
      }
    }
  };

  // -------- encoder: 128 steps, 1 barrier/step (ping-pong) --------
  for (int t = 0; t < 128; ++t) {
    const int wi = (t + 1) & 1;
    lstm_step(Wf, hbuf[wi]);
    if (t < 127 && tid < 80) {  // stage x(t+1) into write buffer
      int r = tid / 5, d = tid - (tid / 5) * 5;
      hbuf[wi][r][256 + d] = (__bf16)sk[((size_t)(b0 + r) * 128 + (t + 1)) * 5 + d];
    }
    __syncthreads();
#pragma unroll
    for (int c = 0; c < 9; ++c) a[c] = *(const bf16x8*)&hbuf[wi][col][c * 32 + lgrp * 8];
  }

  // -------- transition: hidden = lrelu(W_enc1 @ h_f + b), cell = lrelu(W_enc1 @ c_f + b) --------
  // a[] holds h_f fragments (hbuf[0]); stage c_f into hbuf[1]
#pragma unroll
  for (int p = 0; p < 2; ++p)
#pragma unroll
    for (int r = 0; r < 4; ++r)
      hbuf[1][lgrp * 4 + r][(ut2 + p) * 16 + col] = (__bf16)c_reg[p][r];
  __syncthreads();

  {
    bf16x8 ac[8];
#pragma unroll
    for (int c = 0; c < 8; ++c) ac[c] = *(const bf16x8*)&hbuf[1][col][c * 32 + lgrp * 8];
#pragma unroll
    for (int p = 0; p < 2; ++p) {
      const int et = ut2 + p;
      bf16x8 eb[8];
#pragma unroll
      for (int c = 0; c < 8; ++c) eb[c] = Wenc[(et * 8 + c) * 64 + lane];
      const float bv = benc[et * 16 + col];
      f32x4 hacc = {bv, bv, bv, bv};
      f32x4 cacc = {bv, bv, bv, bv};
#pragma unroll
      for (int c = 0; c < 8; ++c) {
        hacc = MFMA16(a[c], eb[c], hacc);
        cacc = MFMA16(ac[c], eb[c], cacc);
      }
#pragma unroll
      for (int r = 0; r < 4; ++r) {
        hbuf[0][lgrp * 4 + r][(ut2 + p) * 16 + col] = (__bf16)lrelu(hacc[r]);  // h(0) of gen
        c_reg[p][r] = lrelu(cacc[r]);                                          // c(0) of gen
      }
    }
  }

  if (tid < 80) {  // x(0) of generator = init_inputs
    int r = tid / 5, d = tid - (tid / 5) * 5;
    hbuf[0][r][256 + d] = (__bf16)initx[(b0 + r) * 5 + d];
  }

  // generator-phase constants
  bf16x8 wout_f[8];
#pragma unroll
  for (int p = 0; p < 2; ++p)
#pragma unroll
    for (int q = 0; q < 4; ++q) {
      bias_v[p * 4 + q] = biasg[q * 256 + (ut2 + p) * 16 + col];
      wih[p * 4 + q] = Wgih[(q * 16 + ut2 + p) * 64 + lane];
    }
#pragma unroll
  for (int c = 0; c < 8; ++c) wout_f[c] = Wout[c * 64 + lane];
  const float bo_v = (col < 5) ? bout[col] : 0.0f;

  __syncthreads();

#pragma unroll
  for (int c = 0; c < 9; ++c) a[c] = *(const bf16x8*)&hbuf[0][col][c * 32 + lgrp * 8];

  // -------- generator: 128 steps, 2 barriers/step --------
  for (int t = 0; t < 128; ++t) {
    const int wi = 1 - (t & 1);
    lstm_step(Wg, hbuf[wi]);
    __syncthreads();  // h(t) visible
#pragma unroll
    for (int c = 0; c < 8; ++c) a[c] = *(const bf16x8*)&hbuf[wi][col][c * 32 + lgrp * 8];
    if (wv == 0) {  // out(t) = lrelu(W_out @ h(t) + b_out); also becomes x(t+1)
      f32x4 oacc = {bo_v, bo_v, bo_v, bo_v};
#pragma unroll
      for (int c = 0; c < 8; ++c) oacc = MFMA16(a[c], wout_f[c], oacc);
      if (col < 5) {
#pragma unroll
        for (int r = 0; r < 4; ++r) {
          float v = lrelu(oacc[r]);
          out[((size_t)(b0 + lgrp * 4 + r) * 128 + t) * 5 + col] = v;
          hbuf[wi][lgrp * 4 + r][256 + col] = (__bf16)v;
        }
      }
    }
    __syncthreads();  // x(t+1) visible
    a[8] = *(const bf16x8*)&hbuf[wi][col][256 + lgrp * 8];
  }
}

extern "C" void kernel_launch(void* const* d_in, const int* in_sizes, int n_in,
                              void* d_out, int out_size, void* d_ws, size_t ws_size,
                              hipStream_t stream) {
  const float* sk = (const float*)d_in[0];
  const float* initx = (const float*)d_in[1];
  const float* W_ih = (const float*)d_in[2];
  const float* W_hh = (const float*)d_in[3];
  const float* b_ih = (const float*)d_in[4];
  const float* b_hh = (const float*)d_in[5];
  const float* W_ih_f = (const float*)d_in[6];
  const float* W_hh_f = (const float*)d_in[7];
  const float* b_ih_f = (const float*)d_in[8];
  const float* b_hh_f = (const float*)d_in[9];
  const float* W_enc = (const float*)d_in[14];
  const float* b_enc = (const float*)d_in[15];
  const float* W_out = (const float*)d_in[16];
  const float* b_out = (const float*)d_in[17];

  char* ws = (char*)d_ws;
  __bf16* Wg = (__bf16*)(ws + 0);           // 524288 B
  __bf16* Wf = (__bf16*)(ws + 524288);      // 524288 B
  __bf16* Wgih = (__bf16*)(ws + 1048576);   // 65536 B
  __bf16* Wfih = (__bf16*)(ws + 1114112);   // 65536 B
  __bf16* Wenc = (__bf16*)(ws + 1179648);   // 131072 B
  __bf16* Wout = (__bf16*)(ws + 1310720);   // 8192 B
  float* biasg = (float*)(ws + 1318912);    // 4096 B
  float* biasf = (float*)(ws + 1323008);    // 4096 B

  pack_gates_k<<<592, 64, 0, stream>>>(W_hh, W_ih, b_ih, b_hh, Wg, Wgih, biasg);
  pack_gates_k<<<592, 64, 0, stream>>>(W_hh_f, W_ih_f, b_ih_f, b_hh_f, Wf, Wfih, biasf);
  pack_enc_k<<<128, 64, 0, stream>>>(W_enc, Wenc);
  pack_out_k<<<8, 64, 0, stream>>>(W_out, Wout);

  rnn_fused<<<128, 512, 0, stream>>>(
      sk, initx,
      (const bf16x8*)Wg, (const bf16x8*)Wgih, biasg,
      (const bf16x8*)Wf, (const bf16x8*)Wfih, biasf,
      (const bf16x8*)Wenc, b_enc,
      (const bf16x8*)Wout, b_out,
      (float*)d_out);
}